// Round 5
// baseline (8307.413 us; speedup 1.0000x reference)
//
#include <hip/hip_runtime.h>
#include <math.h>

#define Bsz 256
#define Tsz 192
#define Fc 8
#define E0c 32
#define E1c 16
#define Hc 512
#define G4 2048
#define DINP 64
#define K1t 576    // 64 + 512
#define K2t 1024   // 512 + 512
#define NBLK 256
#define LDS_A_STRIDE 264   // 256 + 8 pad, in ushorts
#define SCR_STRIDE 65
#define SMEM_BYTES (64 * LDS_A_STRIDE * 2 + 64 * SCR_STRIDE * 4)

typedef __attribute__((ext_vector_type(8))) short short8;
typedef __attribute__((ext_vector_type(4))) float f32x4;

template<int N> struct IC { static constexpr int v = N; };
template<int C, int CMAX, typename F>
__device__ __forceinline__ void static_for(F&& f) {
    if constexpr (C < CMAX) {
        f(IC<C>{});
        static_for<C + 1, CMAX>(f);
    }
}

static __device__ __forceinline__ float bf2f(ushort u) {
    return __uint_as_float(((uint)u) << 16);
}
static __device__ __forceinline__ ushort f2bf(float f) {
    uint u = __float_as_uint(f);
    u = (u + 0x7fffu + ((u >> 16) & 1u)) >> 16;
    return (ushort)u;
}

// ---------- build padded bf16 x, time-major [T][B][64] ----------
__global__ __launch_bounds__(256) void build_x_kernel(
    const float* __restrict__ x_cont, const int* __restrict__ cat0,
    const int* __restrict__ cat1, const float* __restrict__ emb0,
    const float* __restrict__ emb1, ushort* __restrict__ x_bf)
{
    int idx = blockIdx.x * 256 + threadIdx.x;
    if (idx >= Tsz * Bsz * DINP) return;
    int d = idx & 63;
    int row = idx >> 6;          // t*B + b
    int t = row >> 8;
    int b = row & 255;
    float v = 0.f;
    if (d < Fc)                  v = x_cont[(b * Tsz + t) * Fc + d];
    else if (d < Fc + E0c)       v = emb0[cat0[b * Tsz + t] * E0c + (d - Fc)];
    else if (d < Fc + E0c + E1c) v = emb1[cat1[b * Tsz + t] * E1c + (d - Fc - E0c)];
    x_bf[idx] = f2bf(v);
}

// ---------- transpose fp32 [K][2048] -> bf16 out[n][coff + k], row stride ldout ----------
__global__ __launch_bounds__(256) void transpose_w_kernel(
    const float* __restrict__ in, ushort* __restrict__ out, int K, int ldout, int coff)
{
    __shared__ float tile[32][33];
    int k0 = blockIdx.x * 32;
    int n0 = blockIdx.y * 32;
    int tx = threadIdx.x & 31, ty = threadIdx.x >> 5;
    #pragma unroll
    for (int p = 0; p < 4; ++p) {
        int k = k0 + ty + p * 8;
        tile[ty + p * 8][tx] = (k < K) ? in[k * G4 + n0 + tx] : 0.f;
    }
    __syncthreads();
    #pragma unroll
    for (int p = 0; p < 4; ++p) {
        int nl = ty + p * 8;
        out[(size_t)(n0 + nl) * ldout + coff + k0 + tx] = f2bf(tile[tx][nl]);
    }
}

// ---------- grid barrier: monotonic counter, device scope ----------
static __device__ __forceinline__ void grid_barrier(uint* bar, uint target) {
    __syncthreads();
    if (threadIdx.x == 0) {
        __threadfence();
        __hip_atomic_fetch_add(bar, 1u, __ATOMIC_RELEASE, __HIP_MEMORY_SCOPE_AGENT);
        while (__hip_atomic_load(bar, __ATOMIC_ACQUIRE, __HIP_MEMORY_SCOPE_AGENT) < target)
            __builtin_amdgcn_s_sleep(2);
        __threadfence();
    }
    __syncthreads();
}

// ---------- one layer's persistent loop ----------
// Block tile: 64 batch rows (m0..) x 16 h-cols (j0..) x 4 gates = 64 z-cols.
// Wave (kw,ng): K-half kw, gates {2ng, 2ng+1}; computes all 4 m-frags over its K-half.
// Weights: Breg[2][KH] = 128 VGPRs (layer2) per lane, persistent across all timesteps.
template<int KL, int KSPLIT, int LDA>
static __device__ __forceinline__ void run_layer(
    const ushort* __restrict__ srcA,   // [T][B][LDA] input activations
    ushort* __restrict__ hbuf,         // [T][B][512] own h (recurrent src + out)
    const ushort* __restrict__ Wt,     // [2048][KL] bf16 transposed weights
    const float* __restrict__ bias,
    ushort* As, float* scr, uint* bar, int m0, int j0, int is_l2)
{
    constexpr int TOTKS = KL / 32;     // total k-steps
    constexpr int KH = TOTKS / 2;      // k-steps per wave k-half
    constexpr int NCH = (KL + 255) / 256;
    int tid = threadIdx.x;
    int lane = tid & 63, wv = tid >> 6;
    int lane15 = lane & 15, quad = lane >> 4;
    int kw = wv & 1, ng = wv >> 1;

    // preload this wave's K-half of the weights into registers (all indices compile-time)
    short8 Breg[2][KH];
    #pragma unroll
    for (int nf = 0; nf < 2; ++nf) {
        int zc = (ng * 2 + nf) * Hc + j0 + lane15;
        const ushort* bp = Wt + (size_t)zc * KL + (size_t)(kw * KH) * 32 + quad * 8;
        #pragma unroll
        for (int ks = 0; ks < KH; ++ks)
            Breg[nf][ks] = *(const short8*)(bp + ks * 32);
    }

    int jj = tid & 15, rg = tid >> 4;
    float bi = bias[j0 + jj];
    float bf_ = bias[Hc + j0 + jj];
    float bg = bias[2 * Hc + j0 + jj];
    float bo = bias[3 * Hc + j0 + jj];
    float cst[4] = {0.f, 0.f, 0.f, 0.f};

    for (int s = 0; s <= Tsz; ++s) {
        int t = is_l2 ? s - 1 : s;
        bool active = is_l2 ? (s >= 1) : (s < Tsz);
        if (active) {
            const ushort* A0 = srcA + (size_t)t * Bsz * LDA;
            const ushort* A1 = hbuf + (size_t)(t - 1) * Bsz * Hc;
            bool hasPrev = (t > 0);
            f32x4 acc[4][2];
            #pragma unroll
            for (int mf = 0; mf < 4; ++mf)
                #pragma unroll
                for (int nf = 0; nf < 2; ++nf)
                    acc[mf][nf] = (f32x4){0.f, 0.f, 0.f, 0.f};

            static_for<0, NCH>([&](auto Cc) {
                constexpr int C = decltype(Cc)::v;
                constexpr int KC = (KL - C * 256 >= 256) ? 256 : (KL - C * 256);
                constexpr int SPR = KC / 8;             // 16B segs per row
                constexpr int ITERS = 64 * SPR / 256;
                #pragma unroll
                for (int i = 0; i < ITERS; ++i) {
                    int idx = tid + i * 256;
                    int row = idx / SPR;
                    int ss = idx - row * SPR;
                    int kglob = C * 256 + ss * 8;
                    uint4 v = {0u, 0u, 0u, 0u};
                    if (kglob < KSPLIT)
                        v = *(const uint4*)(A0 + (size_t)(m0 + row) * LDA + kglob);
                    else if (hasPrev)
                        v = *(const uint4*)(A1 + (size_t)(m0 + row) * Hc + (kglob - KSPLIT));
                    *(uint4*)&As[row * LDS_A_STRIDE + ss * 8] = v;
                }
                __syncthreads();
                #pragma unroll
                for (int kk = 0; kk < KC / 32; ++kk) {
                    const int g = C * 8 + kk;                  // global k-step (const)
                    const int own = (g >= KH) ? 1 : 0;         // const
                    const int bidx = g - own * KH;             // const -> Breg stays in regs
                    if (own == kw) {                           // wave-uniform branch
                        short8 a[4];
                        #pragma unroll
                        for (int mf = 0; mf < 4; ++mf)
                            a[mf] = *(const short8*)&As[(mf * 16 + lane15) * LDS_A_STRIDE + kk * 32 + quad * 8];
                        #pragma unroll
                        for (int mf = 0; mf < 4; ++mf) {
                            acc[mf][0] = __builtin_amdgcn_mfma_f32_16x16x32_bf16(a[mf], Breg[0][bidx], acc[mf][0], 0, 0, 0);
                            acc[mf][1] = __builtin_amdgcn_mfma_f32_16x16x32_bf16(a[mf], Breg[1][bidx], acc[mf][1], 0, 0, 0);
                        }
                    }
                }
                __syncthreads();
            });

            // combine the two K-half partials through scr LDS (two-phase)
            if (kw == 0) {
                #pragma unroll
                for (int mf = 0; mf < 4; ++mf)
                    #pragma unroll
                    for (int nf = 0; nf < 2; ++nf)
                        #pragma unroll
                        for (int r = 0; r < 4; ++r)
                            scr[(mf * 16 + quad * 4 + r) * SCR_STRIDE +
                                (ng * 2 + nf) * 16 + lane15] = acc[mf][nf][r];
            }
            __syncthreads();
            if (kw == 1) {
                #pragma unroll
                for (int mf = 0; mf < 4; ++mf)
                    #pragma unroll
                    for (int nf = 0; nf < 2; ++nf)
                        #pragma unroll
                        for (int r = 0; r < 4; ++r)
                            scr[(mf * 16 + quad * 4 + r) * SCR_STRIDE +
                                (ng * 2 + nf) * 16 + lane15] += acc[mf][nf][r];
            }
            __syncthreads();

            // epilogue: thread owns col jj, rows rg + q*16
            #pragma unroll
            for (int q = 0; q < 4; ++q) {
                int row = rg + q * 16;
                const float* sr = scr + row * SCR_STRIDE;
                float zi = sr[jj] + bi;
                float zf = sr[16 + jj] + bf_;
                float zg = sr[32 + jj] + bg;
                float zo = sr[48 + jj] + bo;
                float ig = 1.f / (1.f + __expf(-zi));
                float fg = 1.f / (1.f + __expf(-zf));
                float gg = tanhf(zg);
                float og = 1.f / (1.f + __expf(-zo));
                float cn = fg * cst[q] + ig * gg;
                cst[q] = cn;
                float hn = og * tanhf(cn);
                hbuf[(size_t)(t * Bsz + m0 + row) * Hc + j0 + jj] = f2bf(hn);
            }
        }
        grid_barrier(bar, (uint)(s + 1) * NBLK);
    }
}

// ---------- the persistent kernel (plain launch; 1 block/CU by LDS+VGPR pressure) ----------
__global__ __launch_bounds__(256, 1) void deepar_persistent(
    const ushort* __restrict__ x_bf,
    const ushort* __restrict__ Wt1, const ushort* __restrict__ Wt2,
    const float* __restrict__ b1, const float* __restrict__ b2,
    ushort* __restrict__ h1, ushort* __restrict__ h2,
    const float* __restrict__ Wmu, const float* __restrict__ bmu,
    const float* __restrict__ Wsig, const float* __restrict__ bsig,
    float* __restrict__ out, uint* __restrict__ bar)
{
    extern __shared__ char smem[];
    ushort* As = (ushort*)smem;                                 // 64 x 264 ushort
    float* scr = (float*)(smem + 64 * LDS_A_STRIDE * 2);        // 64 x 65 fp32

    int bid = blockIdx.x;
    int is_l2 = (bid >= 128);
    int lb = is_l2 ? bid - 128 : bid;
    int m0 = (lb >> 5) * 64;
    int j0 = (lb & 31) * 16;

    if (!is_l2)
        run_layer<K1t, DINP, DINP>(x_bf, h1, Wt1, b1, As, scr, bar, m0, j0, 0);
    else
        run_layer<K2t, Hc, Hc>(h1, h2, Wt2, b2, As, scr, bar, m0, j0, 1);

    // ---- heads: all h2 published by the final grid barrier ----
    int lane = threadIdx.x & 63, wv = threadIdx.x >> 6;
    int gw = bid * 4 + wv;                      // 1024 waves
    float wm[8], wsg[8];
    #pragma unroll
    for (int i = 0; i < 8; ++i) {
        wm[i] = Wmu[lane * 8 + i];
        wsg[i] = Wsig[lane * 8 + i];
    }
    float bmu0 = bmu[0], bsg0 = bsig[0];
    for (int r = gw; r < Bsz * Tsz; r += NBLK * 4) {
        const ushort* hp = h2 + (size_t)r * Hc + lane * 8;
        short8 hv = *(const short8*)hp;
        float smu = 0.f, ssg = 0.f;
        #pragma unroll
        for (int i = 0; i < 8; ++i) {
            float f = bf2f((ushort)hv[i]);
            smu += f * wm[i];
            ssg += f * wsg[i];
        }
        #pragma unroll
        for (int off = 32; off > 0; off >>= 1) {
            smu += __shfl_down(smu, off, 64);
            ssg += __shfl_down(ssg, off, 64);
        }
        if (lane == 0) {
            int t = r >> 8, b = r & 255;
            int oi = b * Tsz + t;
            float sg = ssg + bsg0;
            float sp = sg > 0.f ? sg + log1pf(__expf(-sg)) : log1pf(__expf(sg));
            out[oi] = smu + bmu0;
            out[Bsz * Tsz + oi] = sp;
        }
    }
}

extern "C" void kernel_launch(void* const* d_in, const int* in_sizes, int n_in,
                              void* d_out, int out_size, void* d_ws, size_t ws_size,
                              hipStream_t stream) {
    const float* x_cont = (const float*)d_in[0];
    const int*   cat0   = (const int*)d_in[1];
    const int*   cat1   = (const int*)d_in[2];
    const float* emb0   = (const float*)d_in[3];
    const float* emb1   = (const float*)d_in[4];
    const float* Wk1    = (const float*)d_in[5];
    const float* Wr1    = (const float*)d_in[6];
    const float* b1     = (const float*)d_in[7];
    const float* Wk2    = (const float*)d_in[8];
    const float* Wr2    = (const float*)d_in[9];
    const float* b2     = (const float*)d_in[10];
    const float* Wmu    = (const float*)d_in[11];
    const float* bmu    = (const float*)d_in[12];
    const float* Wsig   = (const float*)d_in[13];
    const float* bsig   = (const float*)d_in[14];
    float* out = (float*)d_out;

    char* ws = (char*)d_ws;
    uint*   bar  = (uint*)ws;                                   ws += 256;
    ushort* x_bf = (ushort*)ws;                                 ws += (size_t)Tsz * Bsz * DINP * 2;
    ushort* Wt1  = (ushort*)ws;                                 ws += (size_t)G4 * K1t * 2;
    ushort* Wt2  = (ushort*)ws;                                 ws += (size_t)G4 * K2t * 2;
    ushort* h1   = (ushort*)ws;                                 ws += (size_t)Tsz * Bsz * Hc * 2;
    ushort* h2   = (ushort*)ws;                                 ws += (size_t)Tsz * Bsz * Hc * 2;

    hipMemsetAsync(bar, 0, 256, stream);

    build_x_kernel<<<(Tsz * Bsz * DINP + 255) / 256, 256, 0, stream>>>(
        x_cont, cat0, cat1, emb0, emb1, x_bf);
    // Wt1 = [Wk1^T (cols 0..63) | Wr1^T (cols 64..575)], row stride 576
    transpose_w_kernel<<<dim3(2, 64), 256, 0, stream>>>(Wk1, Wt1, 56, K1t, 0);
    transpose_w_kernel<<<dim3(16, 64), 256, 0, stream>>>(Wr1, Wt1, Hc, K1t, DINP);
    // Wt2 = [Wk2^T (0..511) | Wr2^T (512..1023)], row stride 1024
    transpose_w_kernel<<<dim3(16, 64), 256, 0, stream>>>(Wk2, Wt2, Hc, K2t, 0);
    transpose_w_kernel<<<dim3(16, 64), 256, 0, stream>>>(Wr2, Wt2, Hc, K2t, Hc);

    deepar_persistent<<<dim3(NBLK), dim3(256), SMEM_BYTES, stream>>>(
        x_bf, Wt1, Wt2, b1, b2, h1, h2, Wmu, bmu, Wsig, bsig, out, bar);
}

// Round 6
// 7360.886 us; speedup vs baseline: 1.1286x; 1.1286x over previous
//
#include <hip/hip_runtime.h>
#include <math.h>

#define Bsz 256
#define Tsz 192
#define Fc 8
#define E0c 32
#define E1c 16
#define Hc 512
#define G4 2048
#define DINP 64
#define K1t 576    // 64 + 512
#define K2t 1024   // 512 + 512
#define NBLK 256
#define KPAD1 584  // 576+8 ushorts, row = 1168 B (16B-aligned)
#define KPAD2 1032 // 1024+8 ushorts, row = 2064 B (16B-aligned)
#define LDSB_BYTES (32 * KPAD2 * 2)   // 66048

typedef __attribute__((ext_vector_type(8))) short short8;
typedef __attribute__((ext_vector_type(4))) float f32x4;

static __device__ __forceinline__ float bf2f(ushort u) {
    return __uint_as_float(((uint)u) << 16);
}
static __device__ __forceinline__ ushort f2bf(float f) {
    uint u = __float_as_uint(f);
    u = (u + 0x7fffu + ((u >> 16) & 1u)) >> 16;
    return (ushort)u;
}

// ---------- build padded bf16 x, time-major [T][B][64] ----------
__global__ __launch_bounds__(256) void build_x_kernel(
    const float* __restrict__ x_cont, const int* __restrict__ cat0,
    const int* __restrict__ cat1, const float* __restrict__ emb0,
    const float* __restrict__ emb1, ushort* __restrict__ x_bf)
{
    int idx = blockIdx.x * 256 + threadIdx.x;
    if (idx >= Tsz * Bsz * DINP) return;
    int d = idx & 63;
    int row = idx >> 6;          // t*B + b
    int t = row >> 8;
    int b = row & 255;
    float v = 0.f;
    if (d < Fc)                  v = x_cont[(b * Tsz + t) * Fc + d];
    else if (d < Fc + E0c)       v = emb0[cat0[b * Tsz + t] * E0c + (d - Fc)];
    else if (d < Fc + E0c + E1c) v = emb1[cat1[b * Tsz + t] * E1c + (d - Fc - E0c)];
    x_bf[idx] = f2bf(v);
}

// ---------- transpose fp32 [K][2048] -> bf16 out[n][coff + k], row stride ldout ----------
__global__ __launch_bounds__(256) void transpose_w_kernel(
    const float* __restrict__ in, ushort* __restrict__ out, int K, int ldout, int coff)
{
    __shared__ float tile[32][33];
    int k0 = blockIdx.x * 32;
    int n0 = blockIdx.y * 32;
    int tx = threadIdx.x & 31, ty = threadIdx.x >> 5;
    #pragma unroll
    for (int p = 0; p < 4; ++p) {
        int k = k0 + ty + p * 8;
        tile[ty + p * 8][tx] = (k < K) ? in[k * G4 + n0 + tx] : 0.f;
    }
    __syncthreads();
    #pragma unroll
    for (int p = 0; p < 4; ++p) {
        int nl = ty + p * 8;
        out[(size_t)(n0 + nl) * ldout + coff + k0 + tx] = f2bf(tile[tx][nl]);
    }
}

// ---------- grid barrier: monotonic counter, device scope ----------
static __device__ __forceinline__ void grid_barrier(uint* bar, uint target) {
    __syncthreads();
    if (threadIdx.x == 0) {
        __threadfence();
        __hip_atomic_fetch_add(bar, 1u, __ATOMIC_RELEASE, __HIP_MEMORY_SCOPE_AGENT);
        while (__hip_atomic_load(bar, __ATOMIC_ACQUIRE, __HIP_MEMORY_SCOPE_AGENT) < target)
            __builtin_amdgcn_s_sleep(2);
        __threadfence();
    }
    __syncthreads();
}

// ---------- one layer's persistent loop ----------
// 128 blocks/layer: 2 m-groups (128 rows) x 64 j-groups (8 h-cols -> 32 z-cols).
// Weights for the block's 32 z-cols live in LDS (loaded once). A-frags read
// straight from global. No __syncthreads inside a timestep.
// Wave wv owns rows m0+wv*32 .. +32 (2 m-frags), all 32 z-cols (2 n-frags).
template<int KS_IN, int KS_TOT, int LDA_IN, int KPADv>
static __device__ __forceinline__ void run_layer(
    const ushort* __restrict__ Ain,    // [T][B][LDA_IN] input activations
    ushort* __restrict__ hbuf,         // [T][B][512] own h (recurrent src + out)
    const ushort* __restrict__ hzero,  // [B][512] zeros
    const ushort* __restrict__ Wt,     // [2048][KS_TOT*32] bf16 transposed
    const float* __restrict__ bias,
    ushort* B_lds, uint* bar, int m0, int j0, int is_l2)
{
    constexpr int KL = KS_TOT * 32;
    constexpr int SEGS = KL / 8;
    int tid = threadIdx.x;
    int lane = tid & 63, wv = tid >> 6;
    int lane15 = lane & 15, quad = lane >> 4;
    int wvm = m0 + wv * 32;

    // ---- load this block's weight slice into LDS once ----
    // LDS row zcl = gate*8 + hc  <-  global z row gate*512 + j0 + hc
    for (int i = tid; i < 32 * SEGS; i += 256) {
        int row = i / SEGS, seg = i - row * SEGS;
        int gz = (row >> 3) * Hc + j0 + (row & 7);
        *(uint4*)&B_lds[row * KPADv + seg * 8] =
            *(const uint4*)(Wt + (size_t)gz * KL + seg * 8);
    }
    __syncthreads();

    int hc = lane15 & 7;
    float bi  = bias[j0 + hc];
    float bf_ = bias[Hc + j0 + hc];
    float bg  = bias[2 * Hc + j0 + hc];
    float bo  = bias[3 * Hc + j0 + hc];
    float cst[2][4] = {{0.f,0.f,0.f,0.f},{0.f,0.f,0.f,0.f}};

    int r0 = wvm + lane15;        // A-frag row, mf=0
    int r1 = wvm + 16 + lane15;   // A-frag row, mf=1
    int ko = quad * 8;            // A/B k sub-offset for this lane

    for (int s = 0; s <= Tsz; ++s) {
        int t = is_l2 ? s - 1 : s;
        bool active = is_l2 ? (s >= 1) : (s < Tsz);
        if (active) {
            const ushort* A0 = Ain + (size_t)t * Bsz * LDA_IN;
            const ushort* A1 = (t > 0) ? (hbuf + (size_t)(t - 1) * Bsz * Hc) : hzero;
            const ushort* a0p = A0 + (size_t)r0 * LDA_IN + ko;
            const ushort* a1p = A0 + (size_t)r1 * LDA_IN + ko;
            const ushort* h0p = A1 + (size_t)r0 * Hc + ko;
            const ushort* h1p = A1 + (size_t)r1 * Hc + ko;

            f32x4 acc[2][2];
            #pragma unroll
            for (int mf = 0; mf < 2; ++mf)
                #pragma unroll
                for (int nf = 0; nf < 2; ++nf)
                    acc[mf][nf] = (f32x4){0.f, 0.f, 0.f, 0.f};

            // region 1: input activations (ksteps 0..KS_IN)
            #pragma unroll
            for (int ks = 0; ks < KS_IN; ++ks) {
                short8 a0 = *(const short8*)(a0p + ks * 32);
                short8 a1 = *(const short8*)(a1p + ks * 32);
                short8 b0 = *(const short8*)&B_lds[lane15 * KPADv + ks * 32 + ko];
                short8 b1 = *(const short8*)&B_lds[(16 + lane15) * KPADv + ks * 32 + ko];
                acc[0][0] = __builtin_amdgcn_mfma_f32_16x16x32_bf16(a0, b0, acc[0][0], 0, 0, 0);
                acc[0][1] = __builtin_amdgcn_mfma_f32_16x16x32_bf16(a0, b1, acc[0][1], 0, 0, 0);
                acc[1][0] = __builtin_amdgcn_mfma_f32_16x16x32_bf16(a1, b0, acc[1][0], 0, 0, 0);
                acc[1][1] = __builtin_amdgcn_mfma_f32_16x16x32_bf16(a1, b1, acc[1][1], 0, 0, 0);
            }
            // region 2: recurrent h (ksteps KS_IN..KS_TOT)
            #pragma unroll
            for (int ks = 0; ks < KS_TOT - KS_IN; ++ks) {
                short8 a0 = *(const short8*)(h0p + ks * 32);
                short8 a1 = *(const short8*)(h1p + ks * 32);
                short8 b0 = *(const short8*)&B_lds[lane15 * KPADv + (KS_IN + ks) * 32 + ko];
                short8 b1 = *(const short8*)&B_lds[(16 + lane15) * KPADv + (KS_IN + ks) * 32 + ko];
                acc[0][0] = __builtin_amdgcn_mfma_f32_16x16x32_bf16(a0, b0, acc[0][0], 0, 0, 0);
                acc[0][1] = __builtin_amdgcn_mfma_f32_16x16x32_bf16(a0, b1, acc[0][1], 0, 0, 0);
                acc[1][0] = __builtin_amdgcn_mfma_f32_16x16x32_bf16(a1, b0, acc[1][0], 0, 0, 0);
                acc[1][1] = __builtin_amdgcn_mfma_f32_16x16x32_bf16(a1, b1, acc[1][1], 0, 0, 0);
            }

            // ---- epilogue: i at (nf0, lane15<8), f at (nf0, lane15>=8),
            //                g at (nf1, lane15<8), o at (nf1, lane15>=8) ----
            #pragma unroll
            for (int mf = 0; mf < 2; ++mf) {
                float zfp[4], zop[4];
                #pragma unroll
                for (int r = 0; r < 4; ++r) {
                    zfp[r] = __shfl_xor(acc[mf][0][r], 8, 64);
                    zop[r] = __shfl_xor(acc[mf][1][r], 8, 64);
                }
                if (lane15 < 8) {
                    #pragma unroll
                    for (int r = 0; r < 4; ++r) {
                        float zi = acc[mf][0][r] + bi;
                        float zf = zfp[r] + bf_;
                        float zg = acc[mf][1][r] + bg;
                        float zo = zop[r] + bo;
                        float ig = 1.f / (1.f + __expf(-zi));
                        float fg = 1.f / (1.f + __expf(-zf));
                        float gg = tanhf(zg);
                        float og = 1.f / (1.f + __expf(-zo));
                        float cn = fg * cst[mf][r] + ig * gg;
                        cst[mf][r] = cn;
                        float hn = og * tanhf(cn);
                        int row = wvm + mf * 16 + quad * 4 + r;
                        hbuf[((size_t)t * Bsz + row) * Hc + j0 + hc] = f2bf(hn);
                    }
                }
            }
        }
        grid_barrier(bar, (uint)(s + 1) * NBLK);
    }
}

// ---------- the persistent kernel ----------
__global__ __launch_bounds__(256, 1) void deepar_persistent(
    const ushort* __restrict__ x_bf,
    const ushort* __restrict__ Wt1, const ushort* __restrict__ Wt2,
    const float* __restrict__ b1, const float* __restrict__ b2,
    ushort* __restrict__ h1, ushort* __restrict__ h2,
    const ushort* __restrict__ hz,
    const float* __restrict__ Wmu, const float* __restrict__ bmu,
    const float* __restrict__ Wsig, const float* __restrict__ bsig,
    float* __restrict__ out, uint* __restrict__ bar)
{
    extern __shared__ char smem[];
    ushort* B_lds = (ushort*)smem;

    int bid = blockIdx.x;
    int is_l2 = (bid >= 128);
    int lb = is_l2 ? bid - 128 : bid;
    int m0 = (lb >> 6) * 128;      // 2 m-groups
    int j0 = (lb & 63) * 8;        // 64 j-groups of 8 h-cols

    if (!is_l2)
        run_layer<2, 18, DINP, KPAD1>(x_bf, h1, hz, Wt1, b1, B_lds, bar, m0, j0, 0);
    else
        run_layer<16, 32, Hc, KPAD2>(h1, h2, hz, Wt2, b2, B_lds, bar, m0, j0, 1);

    // ---- heads: all h2 published by the final grid barrier ----
    int lane = threadIdx.x & 63, wv = threadIdx.x >> 6;
    int gw = bid * 4 + wv;                      // 1024 waves
    float wm[8], wsg[8];
    #pragma unroll
    for (int i = 0; i < 8; ++i) {
        wm[i] = Wmu[lane * 8 + i];
        wsg[i] = Wsig[lane * 8 + i];
    }
    float bmu0 = bmu[0], bsg0 = bsig[0];
    for (int r = gw; r < Bsz * Tsz; r += NBLK * 4) {
        const ushort* hp = h2 + (size_t)r * Hc + lane * 8;
        short8 hv = *(const short8*)hp;
        float smu = 0.f, ssg = 0.f;
        #pragma unroll
        for (int i = 0; i < 8; ++i) {
            float f = bf2f((ushort)hv[i]);
            smu += f * wm[i];
            ssg += f * wsg[i];
        }
        #pragma unroll
        for (int off = 32; off > 0; off >>= 1) {
            smu += __shfl_down(smu, off, 64);
            ssg += __shfl_down(ssg, off, 64);
        }
        if (lane == 0) {
            int t = r >> 8, b = r & 255;
            int oi = b * Tsz + t;
            float sg = ssg + bsg0;
            float sp = sg > 0.f ? sg + log1pf(__expf(-sg)) : log1pf(__expf(sg));
            out[oi] = smu + bmu0;
            out[Bsz * Tsz + oi] = sp;
        }
    }
}

extern "C" void kernel_launch(void* const* d_in, const int* in_sizes, int n_in,
                              void* d_out, int out_size, void* d_ws, size_t ws_size,
                              hipStream_t stream) {
    const float* x_cont = (const float*)d_in[0];
    const int*   cat0   = (const int*)d_in[1];
    const int*   cat1   = (const int*)d_in[2];
    const float* emb0   = (const float*)d_in[3];
    const float* emb1   = (const float*)d_in[4];
    const float* Wk1    = (const float*)d_in[5];
    const float* Wr1    = (const float*)d_in[6];
    const float* b1     = (const float*)d_in[7];
    const float* Wk2    = (const float*)d_in[8];
    const float* Wr2    = (const float*)d_in[9];
    const float* b2     = (const float*)d_in[10];
    const float* Wmu    = (const float*)d_in[11];
    const float* bmu    = (const float*)d_in[12];
    const float* Wsig   = (const float*)d_in[13];
    const float* bsig   = (const float*)d_in[14];
    float* out = (float*)d_out;

    char* ws = (char*)d_ws;
    uint*   bar  = (uint*)ws;                                   ws += 256;
    ushort* x_bf = (ushort*)ws;                                 ws += (size_t)Tsz * Bsz * DINP * 2;
    ushort* Wt1  = (ushort*)ws;                                 ws += (size_t)G4 * K1t * 2;
    ushort* Wt2  = (ushort*)ws;                                 ws += (size_t)G4 * K2t * 2;
    ushort* h1   = (ushort*)ws;                                 ws += (size_t)Tsz * Bsz * Hc * 2;
    ushort* h2   = (ushort*)ws;                                 ws += (size_t)Tsz * Bsz * Hc * 2;
    ushort* hz   = (ushort*)ws;                                 ws += (size_t)Bsz * Hc * 2;

    hipMemsetAsync(bar, 0, 256, stream);
    hipMemsetAsync(hz, 0, (size_t)Bsz * Hc * 2, stream);

    build_x_kernel<<<(Tsz * Bsz * DINP + 255) / 256, 256, 0, stream>>>(
        x_cont, cat0, cat1, emb0, emb1, x_bf);
    // Wt1 = [Wk1^T (cols 0..63) | Wr1^T (cols 64..575)], row stride 576
    transpose_w_kernel<<<dim3(2, 64), 256, 0, stream>>>(Wk1, Wt1, 56, K1t, 0);
    transpose_w_kernel<<<dim3(16, 64), 256, 0, stream>>>(Wr1, Wt1, Hc, K1t, DINP);
    // Wt2 = [Wk2^T (0..511) | Wr2^T (512..1023)], row stride 1024
    transpose_w_kernel<<<dim3(16, 64), 256, 0, stream>>>(Wk2, Wt2, Hc, K2t, 0);
    transpose_w_kernel<<<dim3(16, 64), 256, 0, stream>>>(Wr2, Wt2, Hc, K2t, Hc);

    hipFuncSetAttribute((const void*)deepar_persistent,
                        hipFuncAttributeMaxDynamicSharedMemorySize, LDSB_BYTES);
    deepar_persistent<<<dim3(NBLK), dim3(256), LDSB_BYTES, stream>>>(
        x_bf, Wt1, Wt2, b1, b2, h1, h2, hz, Wmu, bmu, Wsig, bsig, out, bar);
}

// Round 7
// 3000.835 us; speedup vs baseline: 2.7684x; 2.4529x over previous
//
#include <hip/hip_runtime.h>
#include <math.h>

#define Bsz 256
#define Tsz 192
#define Fc 8
#define E0c 32
#define E1c 16
#define Hc 512
#define G4 2048
#define DINP 64
#define K1t 576    // 64 + 512
#define K2t 1024   // 512 + 512
#define NBLK 256
#define LBLK 32    // blocks per (group, layer)
#define KPAD1 584  // 576+8 ushorts (16B-aligned rows)
#define KPAD2 1032 // 1024+8 ushorts
#define LDSB_BYTES (64 * KPAD2 * 2)   // 132096

typedef __attribute__((ext_vector_type(8))) short short8;
typedef __attribute__((ext_vector_type(4))) float f32x4;

static __device__ __forceinline__ float bf2f(ushort u) {
    return __uint_as_float(((uint)u) << 16);
}
static __device__ __forceinline__ ushort f2bf(float f) {
    uint u = __float_as_uint(f);
    u = (u + 0x7fffu + ((u >> 16) & 1u)) >> 16;
    return (ushort)u;
}

// ---------- build padded bf16 x, time-major [T][B][64] ----------
__global__ __launch_bounds__(256) void build_x_kernel(
    const float* __restrict__ x_cont, const int* __restrict__ cat0,
    const int* __restrict__ cat1, const float* __restrict__ emb0,
    const float* __restrict__ emb1, ushort* __restrict__ x_bf)
{
    int idx = blockIdx.x * 256 + threadIdx.x;
    if (idx >= Tsz * Bsz * DINP) return;
    int d = idx & 63;
    int row = idx >> 6;          // t*B + b
    int t = row >> 8;
    int b = row & 255;
    float v = 0.f;
    if (d < Fc)                  v = x_cont[(b * Tsz + t) * Fc + d];
    else if (d < Fc + E0c)       v = emb0[cat0[b * Tsz + t] * E0c + (d - Fc)];
    else if (d < Fc + E0c + E1c) v = emb1[cat1[b * Tsz + t] * E1c + (d - Fc - E0c)];
    x_bf[idx] = f2bf(v);
}

// ---------- transpose fp32 [K][2048] -> bf16 out[n][coff + k], row stride ldout ----------
__global__ __launch_bounds__(256) void transpose_w_kernel(
    const float* __restrict__ in, ushort* __restrict__ out, int K, int ldout, int coff)
{
    __shared__ float tile[32][33];
    int k0 = blockIdx.x * 32;
    int n0 = blockIdx.y * 32;
    int tx = threadIdx.x & 31, ty = threadIdx.x >> 5;
    #pragma unroll
    for (int p = 0; p < 4; ++p) {
        int k = k0 + ty + p * 8;
        tile[ty + p * 8][tx] = (k < K) ? in[k * G4 + n0 + tx] : 0.f;
    }
    __syncthreads();
    #pragma unroll
    for (int p = 0; p < 4; ++p) {
        int nl = ty + p * 8;
        out[(size_t)(n0 + nl) * ldout + coff + k0 + tx] = f2bf(tile[tx][nl]);
    }
}

// ---------- spin-wait (called by thread 0 only) ----------
static __device__ __forceinline__ void wait_ge(const uint* p, uint target) {
    while (__hip_atomic_load(p, __ATOMIC_ACQUIRE, __HIP_MEMORY_SCOPE_AGENT) < target)
        __builtin_amdgcn_s_sleep(1);
}

// ---------- one layer's persistent loop ----------
// Group: 64 batch rows, 32 blocks per layer. Block: 64 rows x 64 z-cols
// (4 gates x 16 h-cols). Wave wv: rows m0+wv*16, all 4 gates.
// Weights in LDS (once). A burst-loaded to registers each step.
template<int KS_IN, int KS_TOT, int LDA_IN, int KPADv>
static __device__ __forceinline__ void run_layer(
    const ushort* __restrict__ Ain,    // [T][B][LDA_IN]
    ushort* __restrict__ hbuf,         // [T][B][512] own h
    const ushort* __restrict__ hz,     // [B][512] zeros
    const ushort* __restrict__ Wt,     // [2048][KS_TOT*32] bf16
    const float* __restrict__ bias,
    ushort* B_lds, uint* bar_own, const uint* bar_dep, int m0, int j0)
{
    constexpr int KL = KS_TOT * 32;
    constexpr int SEGS = KL / 8;
    int tid = threadIdx.x;
    int lane = tid & 63, wv = tid >> 6;
    int lane15 = lane & 15, quad = lane >> 4;

    // ---- weights -> LDS once: LDS row = gate*16 + hcol ----
    for (int i = tid; i < 64 * SEGS; i += 256) {
        int row = i / SEGS, seg = i - row * SEGS;
        int gz = (row >> 4) * Hc + j0 + (row & 15);
        *(uint4*)&B_lds[row * KPADv + seg * 8] =
            *(const uint4*)(Wt + (size_t)gz * KL + seg * 8);
    }
    __syncthreads();

    float bgate[4];
    #pragma unroll
    for (int gt = 0; gt < 4; ++gt) bgate[gt] = bias[gt * Hc + j0 + lane15];
    float cst[4] = {0.f, 0.f, 0.f, 0.f};

    int arow = m0 + wv * 16 + lane15;   // A-fragment row for this lane
    int crow0 = m0 + wv * 16 + quad * 4; // epilogue batch-row base

    for (int t = 0; t < Tsz; ++t) {
        if (tid == 0) {
            if (bar_dep) wait_ge(bar_dep, (uint)(t + 1) * LBLK);
            if (t) wait_ge(bar_own, (uint)t * LBLK);
        }
        __syncthreads();

        const ushort* A0 = Ain + (size_t)t * Bsz * LDA_IN;
        const ushort* A1 = (t > 0) ? (hbuf + (size_t)(t - 1) * Bsz * Hc) : hz;

        // burst: load ALL A-fragments for this step into registers
        short8 areg[KS_TOT];
        {
            const ushort* p0 = A0 + (size_t)arow * LDA_IN + quad * 8;
            #pragma unroll
            for (int ks = 0; ks < KS_IN; ++ks)
                areg[ks] = *(const short8*)(p0 + ks * 32);
            const ushort* p1 = A1 + (size_t)arow * Hc + quad * 8;
            #pragma unroll
            for (int ks = 0; ks < KS_TOT - KS_IN; ++ks)
                areg[KS_IN + ks] = *(const short8*)(p1 + ks * 32);
        }

        f32x4 acc[4];
        #pragma unroll
        for (int gt = 0; gt < 4; ++gt) acc[gt] = (f32x4){0.f, 0.f, 0.f, 0.f};

        #pragma unroll
        for (int ks = 0; ks < KS_TOT; ++ks) {
            #pragma unroll
            for (int gt = 0; gt < 4; ++gt) {
                short8 bfr = *(const short8*)&B_lds[(gt * 16 + lane15) * KPADv + ks * 32 + quad * 8];
                acc[gt] = __builtin_amdgcn_mfma_f32_16x16x32_bf16(areg[ks], bfr, acc[gt], 0, 0, 0);
            }
        }

        // epilogue fully in-register: thread owns col j0+lane15, rows crow0+r
        #pragma unroll
        for (int r = 0; r < 4; ++r) {
            float zi = acc[0][r] + bgate[0];
            float zf = acc[1][r] + bgate[1];
            float zg = acc[2][r] + bgate[2];
            float zo = acc[3][r] + bgate[3];
            float ig = 1.f / (1.f + __expf(-zi));
            float fg = 1.f / (1.f + __expf(-zf));
            float gg = tanhf(zg);
            float og = 1.f / (1.f + __expf(-zo));
            float cn = fg * cst[r] + ig * gg;
            cst[r] = cn;
            float hn = og * tanhf(cn);
            hbuf[((size_t)t * Bsz + crow0 + r) * Hc + j0 + lane15] = f2bf(hn);
        }

        __syncthreads();   // all waves' h-stores done
        if (tid == 0)
            __hip_atomic_fetch_add(bar_own, 1u, __ATOMIC_RELEASE, __HIP_MEMORY_SCOPE_AGENT);
    }
}

// ---------- the persistent kernel ----------
// 256 blocks: group g = bid>>6 (64 batch rows), role = (bid>>5)&1 (layer),
// jb = bid&31 (16 h-cols). Groups are fully independent (batch-parallel).
__global__ __launch_bounds__(256, 1) void deepar_persistent(
    const ushort* __restrict__ x_bf,
    const ushort* __restrict__ Wt1, const ushort* __restrict__ Wt2,
    const float* __restrict__ b1, const float* __restrict__ b2,
    ushort* __restrict__ h1, ushort* __restrict__ h2,
    const ushort* __restrict__ hz,
    const float* __restrict__ Wmu, const float* __restrict__ bmu,
    const float* __restrict__ Wsig, const float* __restrict__ bsig,
    float* __restrict__ out, uint* __restrict__ bar)
{
    extern __shared__ ushort B_lds[];

    int bid = blockIdx.x;
    int g = bid >> 6;
    int role = (bid >> 5) & 1;
    int jb = bid & 31;
    int m0 = g * 64;
    int j0 = jb * 16;
    uint* bar1 = bar + g * 32;        // 128B apart
    uint* bar2 = bar + g * 32 + 16;

    if (role == 0) {
        run_layer<2, 18, DINP, KPAD1>(x_bf, h1, hz, Wt1, b1, B_lds, bar1, nullptr, m0, j0);
        return;
    }
    run_layer<16, 32, Hc, KPAD2>(h1, h2, hz, Wt2, b2, B_lds, bar2, bar1, m0, j0);

    // ---- heads: group g's h2 fully published once bar2 hits Tsz*LBLK ----
    if (threadIdx.x == 0) wait_ge(bar2, (uint)Tsz * LBLK);
    __syncthreads();

    int lane = threadIdx.x & 63, wv = threadIdx.x >> 6;
    float wm[8], wsg[8];
    #pragma unroll
    for (int i = 0; i < 8; ++i) {
        wm[i] = Wmu[lane * 8 + i];
        wsg[i] = Wsig[lane * 8 + i];
    }
    float bmu0 = bmu[0], bsg0 = bsig[0];
    for (int i = jb * 4 + wv; i < 64 * Tsz; i += 128) {
        int b = m0 + (i & 63);
        int t = i >> 6;
        const ushort* hp = h2 + ((size_t)t * Bsz + b) * Hc + lane * 8;
        short8 hv = *(const short8*)hp;
        float smu = 0.f, ssg = 0.f;
        #pragma unroll
        for (int e = 0; e < 8; ++e) {
            float f = bf2f((ushort)hv[e]);
            smu += f * wm[e];
            ssg += f * wsg[e];
        }
        #pragma unroll
        for (int off = 32; off > 0; off >>= 1) {
            smu += __shfl_down(smu, off, 64);
            ssg += __shfl_down(ssg, off, 64);
        }
        if (lane == 0) {
            int oi = b * Tsz + t;
            float sg = ssg + bsg0;
            float sp = sg > 0.f ? sg + log1pf(__expf(-sg)) : log1pf(__expf(sg));
            out[oi] = smu + bmu0;
            out[Bsz * Tsz + oi] = sp;
        }
    }
}

extern "C" void kernel_launch(void* const* d_in, const int* in_sizes, int n_in,
                              void* d_out, int out_size, void* d_ws, size_t ws_size,
                              hipStream_t stream) {
    const float* x_cont = (const float*)d_in[0];
    const int*   cat0   = (const int*)d_in[1];
    const int*   cat1   = (const int*)d_in[2];
    const float* emb0   = (const float*)d_in[3];
    const float* emb1   = (const float*)d_in[4];
    const float* Wk1    = (const float*)d_in[5];
    const float* Wr1    = (const float*)d_in[6];
    const float* b1     = (const float*)d_in[7];
    const float* Wk2    = (const float*)d_in[8];
    const float* Wr2    = (const float*)d_in[9];
    const float* b2     = (const float*)d_in[10];
    const float* Wmu    = (const float*)d_in[11];
    const float* bmu    = (const float*)d_in[12];
    const float* Wsig   = (const float*)d_in[13];
    const float* bsig   = (const float*)d_in[14];
    float* out = (float*)d_out;

    char* ws = (char*)d_ws;
    uint*   bar  = (uint*)ws;                                   ws += 512;
    ushort* x_bf = (ushort*)ws;                                 ws += (size_t)Tsz * Bsz * DINP * 2;
    ushort* Wt1  = (ushort*)ws;                                 ws += (size_t)G4 * K1t * 2;
    ushort* Wt2  = (ushort*)ws;                                 ws += (size_t)G4 * K2t * 2;
    ushort* h1   = (ushort*)ws;                                 ws += (size_t)Tsz * Bsz * Hc * 2;
    ushort* h2   = (ushort*)ws;                                 ws += (size_t)Tsz * Bsz * Hc * 2;
    ushort* hz   = (ushort*)ws;                                 ws += (size_t)Bsz * Hc * 2;

    hipMemsetAsync(bar, 0, 512, stream);
    hipMemsetAsync(hz, 0, (size_t)Bsz * Hc * 2, stream);

    build_x_kernel<<<(Tsz * Bsz * DINP + 255) / 256, 256, 0, stream>>>(
        x_cont, cat0, cat1, emb0, emb1, x_bf);
    transpose_w_kernel<<<dim3(2, 64), 256, 0, stream>>>(Wk1, Wt1, 56, K1t, 0);
    transpose_w_kernel<<<dim3(16, 64), 256, 0, stream>>>(Wr1, Wt1, Hc, K1t, DINP);
    transpose_w_kernel<<<dim3(16, 64), 256, 0, stream>>>(Wk2, Wt2, Hc, K2t, 0);
    transpose_w_kernel<<<dim3(16, 64), 256, 0, stream>>>(Wr2, Wt2, Hc, K2t, Hc);

    hipFuncSetAttribute((const void*)deepar_persistent,
                        hipFuncAttributeMaxDynamicSharedMemorySize, LDSB_BYTES);
    deepar_persistent<<<dim3(NBLK), dim3(256), LDSB_BYTES, stream>>>(
        x_bf, Wt1, Wt2, b1, b2, h1, h2, hz, Wmu, bmu, Wsig, bsig, out, bar);
}